// Round 12
// baseline (179.114 us; speedup 1.0000x reference)
//
#include <hip/hip_runtime.h>
#include <stdint.h>

// Full solution, ZERO libm calls (H_libm: this pod's hipcc hangs compiling any
// source that calls ocml transcendentals — perfect correlation r0-r11).
// Transcendentals via raw gfx950 ISA: v_log_f32 (log2), v_exp_f32 (2^x).
//
// Forward-pass reduction of the reference:
//   i*(o)  = argmax_i(logits[o,i] + g1[o,i])
//   c[o]   = 2*tanh(2*tanh(weight[o,i*]))
//   y[b,o] = c[o] * x[b,i*] * softmax_i(logits[o,:]+g2[b,o,:])[i*]
// RNG: JAX threefry2x32, partitionable semantics:
//   key(42)=(0,42); fold-like split: kg_j = threefry(key,(0,j));
//   bits32[e] = o0^o1 of threefry(kg,(0,e)); u=(bits>>9|0x3f800000)-1+tiny;
//   gumbel = -ln(-ln(u)).

__device__ __forceinline__ float fast_log2(float x) {
  float r; asm("v_log_f32 %0, %1" : "=v"(r) : "v"(x)); return r;
}
__device__ __forceinline__ float fast_exp2(float x) {
  float r; asm("v_exp_f32 %0, %1" : "=v"(r) : "v"(x)); return r;
}
__device__ __forceinline__ float fast_exp(float x) {   // e^x
  return fast_exp2(x * 1.4426950408889634f);
}
__device__ __forceinline__ float fast_tanh(float w) {  // (e^2w - 1)/(e^2w + 1)
  float t = fast_exp2(w * 2.8853900817779268f);
  return (t - 1.0f) / (t + 1.0f);
}

__device__ __forceinline__ uint32_t rotl32(uint32_t x, int r) {
  return (x << r) | (x >> (32 - r));
}

__device__ __forceinline__ void threefry2x32(uint32_t k0, uint32_t k1,
                                             uint32_t x0, uint32_t x1,
                                             uint32_t& o0, uint32_t& o1) {
  const uint32_t ks2 = k0 ^ k1 ^ 0x1BD11BDAu;
  x0 += k0; x1 += k1;
  const int rotA[4] = {13, 15, 26, 6};
  const int rotB[4] = {17, 29, 16, 24};
#pragma unroll
  for (int g = 0; g < 5; ++g) {
    const int* rots = (g & 1) ? rotB : rotA;
#pragma unroll
    for (int r = 0; r < 4; ++r) {
      x0 += x1; x1 = rotl32(x1, rots[r]); x1 ^= x0;
    }
    const uint32_t ks[3] = {k0, k1, ks2};
    x0 += ks[(g + 1) % 3];
    x1 += ks[(g + 2) % 3] + (uint32_t)(g + 1);
  }
  o0 = x0; o1 = x1;
}

__device__ __forceinline__ uint32_t tf_bits(uint32_t ka, uint32_t kb, uint32_t e) {
  uint32_t r0, r1;
  threefry2x32(ka, kb, 0u, e, r0, r1);
  return r0 ^ r1;
}

// gumbel = -ln(-ln(u)), u = (bits>>9 | 1.0f-mantissa) - 1 + tiny, all via v_log_f32
__device__ __forceinline__ float gumbel_from_bits(uint32_t bits) {
  float f = __uint_as_float((bits >> 9) | 0x3f800000u) - 1.0f;
  float u = f + 1.17549435e-38f;
  float nl = -0.6931471805599453f * fast_log2(u);    // -ln(u) in (0, ~88]
  return -0.6931471805599453f * fast_log2(nl);       // -ln(-ln(u))
}

// grid: 32768 blocks (= 512 o-values x 64 b-groups), 256 threads (4 waves).
__global__ __launch_bounds__(256) void k_fused(const float* __restrict__ x,
                                               const float* __restrict__ weight,
                                               const float* __restrict__ logits,
                                               float* __restrict__ out) {
  const int o    = blockIdx.x & 511;
  const int bg   = blockIdx.x >> 9;   // 0..63
  const int tid  = threadIdx.x;
  const int lane = tid & 63;
  const int wid  = tid >> 6;
  const float* lrow = logits + o * 512;

  // subkeys (fold-like split of key(42) = (0,42))
  uint32_t k1a, k1b, k2a, k2b;
  threefry2x32(0u, 42u, 0u, 0u, k1a, k1b);  // kg1 for g1 (OUT,IN)
  threefry2x32(0u, 42u, 0u, 1u, k2a, k2b);  // kg2 for g2 (B,OUT,IN)

  // ---- phase 1 (block-cooperative): i* = argmax_i(logits[o,i] + g1[o,i]) ----
  float v; int idx;
  {
    const uint32_t e0 = (uint32_t)(o * 512 + tid);
    v   = lrow[tid] + gumbel_from_bits(tf_bits(k1a, k1b, e0));
    idx = tid;
    float v2 = lrow[tid + 256] + gumbel_from_bits(tf_bits(k1a, k1b, e0 + 256u));
    if (v2 > v) { v = v2; idx = tid + 256; }  // tie -> lower index (jnp.argmax)
  }
  for (int off = 32; off > 0; off >>= 1) {
    float ov = __shfl_down(v, off);
    int   oi = __shfl_down(idx, off);
    if (ov > v || (ov == v && oi < idx)) { v = ov; idx = oi; }
  }
  __shared__ float swv[4];
  __shared__ int   swi[4];
  __shared__ int   s_istar;
  __shared__ float s_c;
  if (lane == 0) { swv[wid] = v; swi[wid] = idx; }
  __syncthreads();
  if (tid == 0) {
    float bv = swv[0]; int bi = swi[0];
    for (int w = 1; w < 4; ++w)
      if (swv[w] > bv || (swv[w] == bv && swi[w] < bi)) { bv = swv[w]; bi = swi[w]; }
    s_istar = bi;
    s_c = 2.0f * fast_tanh(2.0f * fast_tanh(weight[o * 512 + bi]));
  }
  __syncthreads();
  const int   isel = s_istar;
  const float c    = s_c;

  // ---- phase 2: one wave per (b, o) row ----
  const int b   = bg * 4 + wid;              // 0..255
  const int row = (b << 9) | o;              // 0..131071
  const uint32_t base = (uint32_t)row << 9;  // flat g2 index base, < 2^26

  float sum = 0.0f, selv = 0.0f;
#pragma unroll
  for (int j = 0; j < 8; ++j) {
    const int i = lane + 64 * j;
    float z  = lrow[i] + gumbel_from_bits(tf_bits(k2a, k2b, base + (uint32_t)i));
    float ev = fast_exp(z);   // z in [~-10, ~21]; exp <= ~2e9, sum <= ~7e11: safe
    sum += ev;
    if (i == isel) selv = ev;
  }
  for (int off = 32; off > 0; off >>= 1) {
    sum  += __shfl_down(sum, off);
    selv += __shfl_down(selv, off);
  }
  if (lane == 0) out[row] = c * x[(b << 9) | isel] * selv / sum;
}

extern "C" void kernel_launch(void* const* d_in, const int* in_sizes, int n_in,
                              void* d_out, int out_size, void* d_ws, size_t ws_size,
                              hipStream_t stream) {
  const float* x      = (const float*)d_in[0];
  const float* weight = (const float*)d_in[1];
  const float* logits = (const float*)d_in[2];
  float* out = (float*)d_out;
  k_fused<<<dim3(512 * 64), dim3(256), 0, stream>>>(x, weight, logits, out);
}